// Round 7
// baseline (197.548 us; speedup 1.0000x reference)
//
#include <hip/hip_runtime.h>
#include <math.h>

#define B_   8
#define N_   2048
#define IN_  256
#define H_   4
#define D_   64
#define C_   256            // H_*D_
#define M_   (B_*N_)        // 16384
#define NEG  0.2f
#define LOG2E 1.4426950408889634f

typedef short bf16x8 __attribute__((ext_vector_type(8)));
typedef float f32x4  __attribute__((ext_vector_type(4)));

__device__ inline ushort f32_to_bf16_rne(float x) {
    union { float f; unsigned u; } c; c.f = x;
    unsigned u = c.u + 0x7FFFu + ((c.u >> 16) & 1u);
    return (ushort)(u >> 16);
}
__device__ inline float bf16_hi_to_f32(ushort u) {
    union { unsigned u; float f; } c; c.u = ((unsigned)u) << 16;
    return c.f;
}
// order-preserving float<->uint for atomicMax over signed floats
__device__ inline uint fenc(float f) {
    uint u = __float_as_uint(f);
    return u ^ (((int)u < 0) ? 0xFFFFFFFFu : 0x80000000u);
}
__device__ inline float fdec(uint u) {
    return __uint_as_float((u & 0x80000000u) ? (u ^ 0x80000000u) : ~u);
}

// ---------------------------------------------------------------------------
// Kernel 0: wprep (64 blocks).
//  - wproj[k][0..3]=LOG2E*W·a_src, [4..7]=LOG2E*W·a_dst (wave per k row)
//  - Wt_hi/Wt_lo[c][k]: split-cast transposed W
//  - block 0 also inits ermLenc (encoded -inf)
// ---------------------------------------------------------------------------
__global__ __launch_bounds__(256) void wprep_kernel(const float* __restrict__ W,
                                                    const float* __restrict__ a_src,
                                                    const float* __restrict__ a_dst,
                                                    ushort* __restrict__ Wt_hi,
                                                    ushort* __restrict__ Wt_lo,
                                                    float* __restrict__ wproj,
                                                    uint* __restrict__ ermLenc) {
    const int t = threadIdx.x, blk = blockIdx.x;
    if (blk == 0 && t < 32) ermLenc[t] = 0u;   // encoded most-negative
    // part A: wproj for 4 k rows (one per wave)
    {
        const int w = t >> 6, lane = t & 63;
        const int k = blk * 4 + w;
        float4 wv = *(const float4*)&W[k * 256 + lane * 4];
        float4 as = *(const float4*)&a_src[lane * 4];
        float4 ad = *(const float4*)&a_dst[lane * 4];
        float ss = wv.x * as.x + wv.y * as.y + wv.z * as.z + wv.w * as.w;
        float sd = wv.x * ad.x + wv.y * ad.y + wv.z * ad.z + wv.w * ad.w;
        #pragma unroll
        for (int off = 1; off < 16; off <<= 1) {
            ss += __shfl_xor(ss, off);
            sd += __shfl_xor(sd, off);
        }
        if ((lane & 15) == 0) {
            int hh = lane >> 4;
            wproj[k * 8 + hh]     = ss * LOG2E;
            wproj[k * 8 + 4 + hh] = sd * LOG2E;
        }
    }
    // part B: split-transpose the same 4 k rows; thread t = column c
    {
        ushort his[4], los[4];
        #pragma unroll
        for (int kk = 0; kk < 4; kk++) {
            float v = W[(blk * 4 + kk) * 256 + t];
            ushort hi = f32_to_bf16_rne(v);
            his[kk] = hi;
            los[kk] = f32_to_bf16_rne(v - bf16_hi_to_f32(hi));
        }
        *(uint2*)&Wt_hi[(size_t)t * 256 + blk * 4] =
            make_uint2(((uint)his[0]) | (((uint)his[1]) << 16), ((uint)his[2]) | (((uint)his[3]) << 16));
        *(uint2*)&Wt_lo[(size_t)t * 256 + blk * 4] =
            make_uint2(((uint)los[0]) | (((uint)los[1]) << 16), ((uint)los[2]) | (((uint)los[3]) << 16));
    }
}

// ---------------------------------------------------------------------------
// Kernel 1: fused split-bf16 MFMA GEMM + scores + er-max atomic.
// Grid (512, 2) = 1024 blocks x 128 thr (2 waves): m-tile 32, c-half 128.
// Wave = 32 m x 64 c (2x4 frags), 3 MFMAs/frag. Register prefetch of next
// K-slice (A: HBM, B: L2) overlaps the MFMA section. Scores on y==0 only.
// ---------------------------------------------------------------------------
#define GP 40   // LDS pitch (ushorts) = 80 B

__global__ __launch_bounds__(128, 2) void gemm_fused(const float* __restrict__ h,
                                                     const ushort* __restrict__ Wt_hi,
                                                     const ushort* __restrict__ Wt_lo,
                                                     const float* __restrict__ wproj,
                                                     ushort* __restrict__ Wht,
                                                     float* __restrict__ elL,
                                                     float* __restrict__ erL,
                                                     uint* __restrict__ ermLenc) {
    __shared__ ushort As_h[32 * GP], As_l[32 * GP];
    __shared__ ushort Bs_h[128 * GP], Bs_l[128 * GP];

    const int t = threadIdx.x;                 // 0..127
    const int m0 = blockIdx.x * 32;
    const int nb = blockIdx.y;
    const int b = m0 >> 11;
    const int wid = t >> 6, lane = t & 63;
    const int c16 = lane & 15, quad = lane >> 4;
    const int arow = t >> 2, al4 = t & 3;      // A staging: 32 rows x 4 k-quarters

    const float*  hp  = h + (size_t)(m0 + arow) * 256 + al4 * 8;
    const ushort* wth = Wt_hi + (size_t)(nb * 128 + t) * 256;
    const ushort* wtl = Wt_lo + (size_t)(nb * 128 + t) * 256;

    // prefetch K-slice 0 into registers
    float4 av0 = *(const float4*)hp;
    float4 av1 = *(const float4*)(hp + 4);
    uint4 pbh[4], pbl[4];
    #pragma unroll
    for (int q = 0; q < 4; q++) {
        pbh[q] = *(const uint4*)(wth + q * 8);
        pbl[q] = *(const uint4*)(wtl + q * 8);
    }

    float s[8] = {};
    f32x4 acc[2][4] = {};

    for (int k0 = 0; k0 < 256; k0 += 32) {
        float va[8] = {av0.x, av0.y, av0.z, av0.w, av1.x, av1.y, av1.z, av1.w};
        ushort hs[8], ls[8];
        #pragma unroll
        for (int e = 0; e < 8; e++) {
            ushort hi = f32_to_bf16_rne(va[e]);
            hs[e] = hi;
            ls[e] = f32_to_bf16_rne(va[e] - bf16_hi_to_f32(hi));
        }
        if (nb == 0) {
            #pragma unroll
            for (int e = 0; e < 8; e++) {
                int kk = k0 + al4 * 8 + e;
                float4 w0 = *(const float4*)&wproj[kk * 8];
                float4 w1 = *(const float4*)&wproj[kk * 8 + 4];
                s[0] += va[e] * w0.x; s[1] += va[e] * w0.y;
                s[2] += va[e] * w0.z; s[3] += va[e] * w0.w;
                s[4] += va[e] * w1.x; s[5] += va[e] * w1.y;
                s[6] += va[e] * w1.z; s[7] += va[e] * w1.w;
            }
        }
        __syncthreads();   // prior iter's frag reads complete
        *(uint2*)&As_h[arow * GP + al4 * 8] =
            make_uint2(((uint)hs[0]) | (((uint)hs[1]) << 16), ((uint)hs[2]) | (((uint)hs[3]) << 16));
        *(uint2*)&As_h[arow * GP + al4 * 8 + 4] =
            make_uint2(((uint)hs[4]) | (((uint)hs[5]) << 16), ((uint)hs[6]) | (((uint)hs[7]) << 16));
        *(uint2*)&As_l[arow * GP + al4 * 8] =
            make_uint2(((uint)ls[0]) | (((uint)ls[1]) << 16), ((uint)ls[2]) | (((uint)ls[3]) << 16));
        *(uint2*)&As_l[arow * GP + al4 * 8 + 4] =
            make_uint2(((uint)ls[4]) | (((uint)ls[5]) << 16), ((uint)ls[6]) | (((uint)ls[7]) << 16));
        #pragma unroll
        for (int q = 0; q < 4; q++) {
            *(uint4*)&Bs_h[t * GP + q * 8] = pbh[q];
            *(uint4*)&Bs_l[t * GP + q * 8] = pbl[q];
        }
        __syncthreads();

        // prefetch next K-slice (overlaps frag reads + MFMA below)
        if (k0 < 224) {
            av0 = *(const float4*)(hp + k0 + 32);
            av1 = *(const float4*)(hp + k0 + 36);
            #pragma unroll
            for (int q = 0; q < 4; q++) {
                pbh[q] = *(const uint4*)(wth + k0 + 32 + q * 8);
                pbl[q] = *(const uint4*)(wtl + k0 + 32 + q * 8);
            }
        }

        bf16x8 a_h[2], a_l[2];
        #pragma unroll
        for (int rw = 0; rw < 2; rw++) {
            a_h[rw] = *(const bf16x8*)&As_h[(rw * 16 + c16) * GP + quad * 8];
            a_l[rw] = *(const bf16x8*)&As_l[(rw * 16 + c16) * GP + quad * 8];
        }
        #pragma unroll
        for (int fc = 0; fc < 4; fc++) {
            const int crow = wid * 64 + fc * 16 + c16;
            bf16x8 bhf = *(const bf16x8*)&Bs_h[crow * GP + quad * 8];
            bf16x8 blf = *(const bf16x8*)&Bs_l[crow * GP + quad * 8];
            #pragma unroll
            for (int rw = 0; rw < 2; rw++) {
                acc[rw][fc] = __builtin_amdgcn_mfma_f32_16x16x32_bf16(a_h[rw], bhf, acc[rw][fc], 0, 0, 0);
                acc[rw][fc] = __builtin_amdgcn_mfma_f32_16x16x32_bf16(a_l[rw], bhf, acc[rw][fc], 0, 0, 0);
                acc[rw][fc] = __builtin_amdgcn_mfma_f32_16x16x32_bf16(a_h[rw], blf, acc[rw][fc], 0, 0, 0);
            }
        }
    }

    // ---- scores epilogue (y==0 blocks only) ----
    if (nb == 0) {
        #pragma unroll
        for (int c = 0; c < 8; c++) { s[c] += __shfl_xor(s[c], 1); s[c] += __shfl_xor(s[c], 2); }
        if (al4 == 0) {
            int n = (m0 + arow) & 2047;
            #pragma unroll
            for (int hh = 0; hh < 4; hh++) {
                elL[(b * 4 + hh) * N_ + n] = s[hh];
                erL[(b * 4 + hh) * N_ + n] = s[4 + hh];
            }
        }
        #pragma unroll
        for (int c = 4; c < 8; c++) {
            #pragma unroll
            for (int off = 4; off < 64; off <<= 1) s[c] = fmaxf(s[c], __shfl_xor(s[c], off));
        }
        if (lane == 0) {
            #pragma unroll
            for (int hh = 0; hh < 4; hh++)
                atomicMax(&ermLenc[b * 4 + hh], fenc(s[4 + hh]));
        }
    }
    // ---- Wht epilogue: bf16 transposed [bh][d][n] ----
    #pragma unroll
    for (int rw = 0; rw < 2; rw++) {
        const int n0 = (m0 + rw * 16 + quad * 4) & 2047;
        #pragma unroll
        for (int fc = 0; fc < 4; fc++) {
            int c = nb * 128 + wid * 64 + fc * 16 + c16, hh = c >> 6, d = c & 63;
            uint2 pk = make_uint2(
                ((uint)f32_to_bf16_rne(acc[rw][fc][0])) | (((uint)f32_to_bf16_rne(acc[rw][fc][1])) << 16),
                ((uint)f32_to_bf16_rne(acc[rw][fc][2])) | (((uint)f32_to_bf16_rne(acc[rw][fc][3])) << 16));
            *(uint2*)&Wht[((size_t)(b * 4 + hh) * 64 + d) * N_ + n0] = pk;
        }
    }
}

// ---------------------------------------------------------------------------
// Kernel 2: attention. Grid (32, 32) = 1024 blocks x 128 thr (2 waves x 32 i).
// Double-buffered LDS (one barrier/iter) + register prefetch of next tile.
// Each staging thread covers a FULL 32-ushort half-row (4x uint4) -- R6 bug
// was covering only 16 of 32.
// p_ij = max(Pi*Ej, Ri*Fj) — branchless, no transcendentals in the loop.
// ---------------------------------------------------------------------------
#define TPA 80   // pitch (ushorts) = 160 B (measured conflict-free in R4)

__global__ __launch_bounds__(128, 2) void attn_kernel(const ushort* __restrict__ Wht,
                                                      const float* __restrict__ elL,
                                                      const float* __restrict__ erL,
                                                      const uint* __restrict__ ermLenc,
                                                      const float* __restrict__ bias,
                                                      float* __restrict__ out) {
    __shared__ ushort Whs[2][64 * TPA];
    __shared__ float E_s[2][64], F_s[2][64];
    const int t = threadIdx.x;                 // 0..127
    const int bh = blockIdx.y, b = bh >> 2, hh = bh & 3;
    const int wid = t >> 6, lane = t & 63;
    const int c16 = lane & 15, quad = lane >> 4;
    const int ibase = blockIdx.x * 64 + wid * 32;
    const int sd = t >> 1, sh = t & 1;         // staging: row d, j-half (32 wide)

    const float erm = fdec(ermLenc[bh]);
    float Pi[2], Ri[2];
    #pragma unroll
    for (int g = 0; g < 2; g++) {
        float e = elL[bh * N_ + ibase + g * 16 + c16];
        float xm = e + erm;
        float mI = fmaxf(xm, NEG * xm);
        Pi[g] = __builtin_amdgcn_exp2f(e - mI);
        Ri[g] = __builtin_amdgcn_exp2f(NEG * e - mI);
    }

    f32x4 acc[2][4] = {};
    f32x4 den[2] = {};
    const bf16x8 ones = {0x3F80, 0x3F80, 0x3F80, 0x3F80,
                         0x3F80, 0x3F80, 0x3F80, 0x3F80};
    const ushort* WhtB = Wht + (size_t)bh * 64 * N_;
    const float* erb = erL + (size_t)bh * N_;
    const ushort* sp = WhtB + (size_t)sd * N_ + sh * 32;

    // prefetch tile 0 (full 32-ushort half-row per thread)
    uint4 w0 = *(const uint4*)sp;
    uint4 w1 = *(const uint4*)(sp + 8);
    uint4 w2 = *(const uint4*)(sp + 16);
    uint4 w3 = *(const uint4*)(sp + 24);
    float ev = (t < 64) ? erb[t] : 0.f;

    for (int jt = 0; jt < 32; jt++) {
        const int buf = jt & 1;
        {
            ushort* dst = &Whs[buf][sd * TPA + sh * 32];
            *(uint4*)(dst)      = w0;
            *(uint4*)(dst + 8)  = w1;
            *(uint4*)(dst + 16) = w2;
            *(uint4*)(dst + 24) = w3;
        }
        if (t < 64) {
            E_s[buf][t] = __builtin_amdgcn_exp2f(ev);
            F_s[buf][t] = __builtin_amdgcn_exp2f(NEG * ev);
        }
        if (jt < 31) {                          // prefetch next tile
            const int j1 = (jt + 1) * 64;
            w0 = *(const uint4*)(sp + j1);
            w1 = *(const uint4*)(sp + j1 + 8);
            w2 = *(const uint4*)(sp + j1 + 16);
            w3 = *(const uint4*)(sp + j1 + 24);
            if (t < 64) ev = erb[j1 + t];
        }
        __syncthreads();
        #pragma unroll
        for (int ks = 0; ks < 2; ks++) {
            const int jb = ks * 32 + quad * 8;
            float4 e0 = *(const float4*)&E_s[buf][jb];
            float4 e1 = *(const float4*)&E_s[buf][jb + 4];
            float4 f0 = *(const float4*)&F_s[buf][jb];
            float4 f1 = *(const float4*)&F_s[buf][jb + 4];
            float E8[8] = {e0.x, e0.y, e0.z, e0.w, e1.x, e1.y, e1.z, e1.w};
            float F8[8] = {f0.x, f0.y, f0.z, f0.w, f1.x, f1.y, f1.z, f1.w};
            bf16x8 bfr[4];
            #pragma unroll
            for (int fd = 0; fd < 4; fd++)
                bfr[fd] = *(const bf16x8*)&Whs[buf][(fd * 16 + c16) * TPA + jb];
            #pragma unroll
            for (int g = 0; g < 2; g++) {
                const float pi = Pi[g], ri = Ri[g];
                uint uu[8];
                #pragma unroll
                for (int j = 0; j < 8; j++) {
                    float p = fmaxf(pi * E8[j], ri * F8[j]);
                    uu[j] = __float_as_uint(p) + 0x8000u;
                }
                union { bf16x8 v; uint u[4]; } af;
                #pragma unroll
                for (int j = 0; j < 4; j++)
                    af.u[j] = __builtin_amdgcn_perm(uu[2 * j + 1], uu[2 * j], 0x07060302u);
                #pragma unroll
                for (int fd = 0; fd < 4; fd++)
                    acc[g][fd] = __builtin_amdgcn_mfma_f32_16x16x32_bf16(af.v, bfr[fd], acc[g][fd], 0, 0, 0);
                den[g] = __builtin_amdgcn_mfma_f32_16x16x32_bf16(af.v, ones, den[g], 0, 0, 0);
            }
        }
    }

    float bl[4];
    #pragma unroll
    for (int fd = 0; fd < 4; fd++) bl[fd] = bias[hh * 64 + fd * 16 + c16];
    #pragma unroll
    for (int g = 0; g < 2; g++)
        #pragma unroll
        for (int r = 0; r < 4; r++) {
            int i = ibase + g * 16 + quad * 4 + r;
            float inv = 1.0f / den[g][r];
            float* dst = out + (size_t)(b * N_ + i) * C_ + hh * 64;
            #pragma unroll
            for (int fd = 0; fd < 4; fd++)
                dst[fd * 16 + c16] = acc[g][fd][r] * inv + bl[fd];
        }
}

// ---------------------------------------------------------------------------
extern "C" void kernel_launch(void* const* d_in, const int* in_sizes, int n_in,
                              void* d_out, int out_size, void* d_ws, size_t ws_size,
                              hipStream_t stream) {
    const float* h     = (const float*)d_in[0];
    const float* W     = (const float*)d_in[1];
    const float* a_src = (const float*)d_in[2];
    const float* a_dst = (const float*)d_in[3];
    const float* bias  = (const float*)d_in[4];
    float* out = (float*)d_out;

    ushort* Wt_hi = (ushort*)d_ws;                       // 256*256
    ushort* Wt_lo = Wt_hi + 256 * 256;
    ushort* Wht   = Wt_lo + 256 * 256;                   // M_*C_ bf16 [bh][d][n]
    float*  wproj = (float*)(Wht + (size_t)M_ * C_);     // 256*8
    float*  elL   = wproj + 256 * 8;
    float*  erL   = elL + 32 * N_;
    uint*   ermLe = (uint*)(erL + 32 * N_);              // 32 encoded maxima

    wprep_kernel<<<64, 256, 0, stream>>>(W, a_src, a_dst, Wt_hi, Wt_lo, wproj, ermLe);
    gemm_fused<<<dim3(512, 2), 128, 0, stream>>>(h, Wt_hi, Wt_lo, wproj, Wht, elL, erL, ermLe);
    attn_kernel<<<dim3(32, 32), 128, 0, stream>>>(Wht, elL, erL, ermLe, bias, out);
}

// Round 8
// 152.440 us; speedup vs baseline: 1.2959x; 1.2959x over previous
//
#include <hip/hip_runtime.h>
#include <math.h>

#define B_   8
#define N_   2048
#define IN_  256
#define H_   4
#define D_   64
#define C_   256            // H_*D_
#define M_   (B_*N_)        // 16384
#define NEG  0.2f
#define LOG2E 1.4426950408889634f

typedef short bf16x8 __attribute__((ext_vector_type(8)));
typedef float f32x4  __attribute__((ext_vector_type(4)));

__device__ inline ushort f32_to_bf16_rne(float x) {
    union { float f; unsigned u; } c; c.f = x;
    unsigned u = c.u + 0x7FFFu + ((c.u >> 16) & 1u);
    return (ushort)(u >> 16);
}
__device__ inline float bf16_hi_to_f32(ushort u) {
    union { unsigned u; float f; } c; c.u = ((unsigned)u) << 16;
    return c.f;
}
// order-preserving float<->uint for atomicMax over signed floats
__device__ inline uint fenc(float f) {
    uint u = __float_as_uint(f);
    return u ^ (((int)u < 0) ? 0xFFFFFFFFu : 0x80000000u);
}
__device__ inline float fdec(uint u) {
    return __uint_as_float((u & 0x80000000u) ? (u ^ 0x80000000u) : ~u);
}

// ---------------------------------------------------------------------------
// Kernel 0: wprep (64 blocks).
//  - wproj[k][0..3]=LOG2E*W·a_src, [4..7]=LOG2E*W·a_dst (wave per k row)
//  - Wt_hi/Wt_lo[c][k]: split-cast transposed W
//  - block 0 also inits ermLenc (encoded -inf)
// ---------------------------------------------------------------------------
__global__ __launch_bounds__(256) void wprep_kernel(const float* __restrict__ W,
                                                    const float* __restrict__ a_src,
                                                    const float* __restrict__ a_dst,
                                                    ushort* __restrict__ Wt_hi,
                                                    ushort* __restrict__ Wt_lo,
                                                    float* __restrict__ wproj,
                                                    uint* __restrict__ ermLenc) {
    const int t = threadIdx.x, blk = blockIdx.x;
    if (blk == 0 && t < 32) ermLenc[t] = 0u;   // encoded most-negative
    {
        const int w = t >> 6, lane = t & 63;
        const int k = blk * 4 + w;
        float4 wv = *(const float4*)&W[k * 256 + lane * 4];
        float4 as = *(const float4*)&a_src[lane * 4];
        float4 ad = *(const float4*)&a_dst[lane * 4];
        float ss = wv.x * as.x + wv.y * as.y + wv.z * as.z + wv.w * as.w;
        float sd = wv.x * ad.x + wv.y * ad.y + wv.z * ad.z + wv.w * ad.w;
        #pragma unroll
        for (int off = 1; off < 16; off <<= 1) {
            ss += __shfl_xor(ss, off);
            sd += __shfl_xor(sd, off);
        }
        if ((lane & 15) == 0) {
            int hh = lane >> 4;
            wproj[k * 8 + hh]     = ss * LOG2E;
            wproj[k * 8 + 4 + hh] = sd * LOG2E;
        }
    }
    {
        ushort his[4], los[4];
        #pragma unroll
        for (int kk = 0; kk < 4; kk++) {
            float v = W[(blk * 4 + kk) * 256 + t];
            ushort hi = f32_to_bf16_rne(v);
            his[kk] = hi;
            los[kk] = f32_to_bf16_rne(v - bf16_hi_to_f32(hi));
        }
        *(uint2*)&Wt_hi[(size_t)t * 256 + blk * 4] =
            make_uint2(((uint)his[0]) | (((uint)his[1]) << 16), ((uint)his[2]) | (((uint)his[3]) << 16));
        *(uint2*)&Wt_lo[(size_t)t * 256 + blk * 4] =
            make_uint2(((uint)los[0]) | (((uint)los[1]) << 16), ((uint)los[2]) | (((uint)los[3]) << 16));
    }
}

// ---------------------------------------------------------------------------
// Kernel 1: fused split-bf16 MFMA GEMM + scores + er-max atomic.
// Grid (256, 4) = 1024 blocks x 128 thr (2 waves). Block: 64 m x 64 c.
// m-tile 64 => Wht writes cover full 128-B spans per d-row (clean writeback;
// R7's m-tile 32 caused 10x write amplification). K-slice register prefetch.
// Wave = 32 m x 64 c (2x4 frags), 3 MFMAs/frag (hi*hi+lo*hi+hi*lo ~ f32).
// ---------------------------------------------------------------------------
#define GP 40   // LDS pitch (ushorts) = 80 B

__global__ __launch_bounds__(128, 2) void gemm_fused(const float* __restrict__ h,
                                                     const ushort* __restrict__ Wt_hi,
                                                     const ushort* __restrict__ Wt_lo,
                                                     const float* __restrict__ wproj,
                                                     ushort* __restrict__ Wht,
                                                     float* __restrict__ elL,
                                                     float* __restrict__ erL,
                                                     uint* __restrict__ ermLenc) {
    __shared__ ushort As_h[64 * GP], As_l[64 * GP];
    __shared__ ushort Bs_h[64 * GP], Bs_l[64 * GP];

    const int t = threadIdx.x;                 // 0..127
    const int m0 = blockIdx.x * 64;
    const int nb = blockIdx.y;                 // 0..3 (== head, since tile=64)
    const int b = m0 >> 11;
    const int wid = t >> 6, lane = t & 63;
    const int c16 = lane & 15, quad = lane >> 4;
    const int arow = t >> 1, akh = t & 1;      // staging: row (64), k-half (16)

    const float*  hp  = h + (size_t)(m0 + arow) * 256 + akh * 16;
    const ushort* wth = Wt_hi + (size_t)(nb * 64 + arow) * 256 + akh * 16;
    const ushort* wtl = Wt_lo + (size_t)(nb * 64 + arow) * 256 + akh * 16;

    // prefetch K-slice 0
    float4 av[4];
    #pragma unroll
    for (int q = 0; q < 4; q++) av[q] = *(const float4*)(hp + q * 4);
    uint4 pbh[2], pbl[2];
    pbh[0] = *(const uint4*)(wth);     pbh[1] = *(const uint4*)(wth + 8);
    pbl[0] = *(const uint4*)(wtl);     pbl[1] = *(const uint4*)(wtl + 8);

    float s[8] = {};
    f32x4 acc[2][4] = {};

    for (int k0 = 0; k0 < 256; k0 += 32) {
        float va[16];
        #pragma unroll
        for (int q = 0; q < 4; q++) {
            va[q * 4 + 0] = av[q].x; va[q * 4 + 1] = av[q].y;
            va[q * 4 + 2] = av[q].z; va[q * 4 + 3] = av[q].w;
        }
        ushort hs[16], ls[16];
        #pragma unroll
        for (int e = 0; e < 16; e++) {
            ushort hi = f32_to_bf16_rne(va[e]);
            hs[e] = hi;
            ls[e] = f32_to_bf16_rne(va[e] - bf16_hi_to_f32(hi));
        }
        if (nb == 0) {
            #pragma unroll
            for (int e = 0; e < 16; e++) {
                int kk = k0 + akh * 16 + e;
                float4 w0 = *(const float4*)&wproj[kk * 8];
                float4 w1 = *(const float4*)&wproj[kk * 8 + 4];
                s[0] += va[e] * w0.x; s[1] += va[e] * w0.y;
                s[2] += va[e] * w0.z; s[3] += va[e] * w0.w;
                s[4] += va[e] * w1.x; s[5] += va[e] * w1.y;
                s[6] += va[e] * w1.z; s[7] += va[e] * w1.w;
            }
        }
        __syncthreads();   // prior iter's frag reads complete
        {
            ushort* dh = &As_h[arow * GP + akh * 16];
            ushort* dl = &As_l[arow * GP + akh * 16];
            *(uint4*)dh = make_uint4(((uint)hs[0]) | (((uint)hs[1]) << 16), ((uint)hs[2]) | (((uint)hs[3]) << 16),
                                     ((uint)hs[4]) | (((uint)hs[5]) << 16), ((uint)hs[6]) | (((uint)hs[7]) << 16));
            *(uint4*)(dh + 8) = make_uint4(((uint)hs[8]) | (((uint)hs[9]) << 16), ((uint)hs[10]) | (((uint)hs[11]) << 16),
                                           ((uint)hs[12]) | (((uint)hs[13]) << 16), ((uint)hs[14]) | (((uint)hs[15]) << 16));
            *(uint4*)dl = make_uint4(((uint)ls[0]) | (((uint)ls[1]) << 16), ((uint)ls[2]) | (((uint)ls[3]) << 16),
                                     ((uint)ls[4]) | (((uint)ls[5]) << 16), ((uint)ls[6]) | (((uint)ls[7]) << 16));
            *(uint4*)(dl + 8) = make_uint4(((uint)ls[8]) | (((uint)ls[9]) << 16), ((uint)ls[10]) | (((uint)ls[11]) << 16),
                                           ((uint)ls[12]) | (((uint)ls[13]) << 16), ((uint)ls[14]) | (((uint)ls[15]) << 16));
            *(uint4*)&Bs_h[arow * GP + akh * 16]     = pbh[0];
            *(uint4*)&Bs_h[arow * GP + akh * 16 + 8] = pbh[1];
            *(uint4*)&Bs_l[arow * GP + akh * 16]     = pbl[0];
            *(uint4*)&Bs_l[arow * GP + akh * 16 + 8] = pbl[1];
        }
        __syncthreads();

        // prefetch next K-slice (overlaps frag reads + MFMA)
        if (k0 < 224) {
            #pragma unroll
            for (int q = 0; q < 4; q++) av[q] = *(const float4*)(hp + k0 + 32 + q * 4);
            pbh[0] = *(const uint4*)(wth + k0 + 32);
            pbh[1] = *(const uint4*)(wth + k0 + 40);
            pbl[0] = *(const uint4*)(wtl + k0 + 32);
            pbl[1] = *(const uint4*)(wtl + k0 + 40);
        }

        bf16x8 a_h[2], a_l[2];
        #pragma unroll
        for (int rw = 0; rw < 2; rw++) {
            a_h[rw] = *(const bf16x8*)&As_h[(wid * 32 + rw * 16 + c16) * GP + quad * 8];
            a_l[rw] = *(const bf16x8*)&As_l[(wid * 32 + rw * 16 + c16) * GP + quad * 8];
        }
        #pragma unroll
        for (int fc = 0; fc < 4; fc++) {
            bf16x8 bhf = *(const bf16x8*)&Bs_h[(fc * 16 + c16) * GP + quad * 8];
            bf16x8 blf = *(const bf16x8*)&Bs_l[(fc * 16 + c16) * GP + quad * 8];
            #pragma unroll
            for (int rw = 0; rw < 2; rw++) {
                acc[rw][fc] = __builtin_amdgcn_mfma_f32_16x16x32_bf16(a_h[rw], bhf, acc[rw][fc], 0, 0, 0);
                acc[rw][fc] = __builtin_amdgcn_mfma_f32_16x16x32_bf16(a_l[rw], bhf, acc[rw][fc], 0, 0, 0);
                acc[rw][fc] = __builtin_amdgcn_mfma_f32_16x16x32_bf16(a_h[rw], blf, acc[rw][fc], 0, 0, 0);
            }
        }
    }

    // ---- scores epilogue (y==0 blocks only) ----
    if (nb == 0) {
        #pragma unroll
        for (int c = 0; c < 8; c++) s[c] += __shfl_xor(s[c], 1);   // pair = same row
        if (akh == 0) {
            int n = (m0 + arow) & 2047;
            #pragma unroll
            for (int hh = 0; hh < 4; hh++) {
                elL[(b * 4 + hh) * N_ + n] = s[hh];
                erL[(b * 4 + hh) * N_ + n] = s[4 + hh];
            }
        }
        #pragma unroll
        for (int c = 4; c < 8; c++) {
            #pragma unroll
            for (int off = 2; off < 64; off <<= 1) s[c] = fmaxf(s[c], __shfl_xor(s[c], off));
        }
        if (lane == 0) {
            #pragma unroll
            for (int hh = 0; hh < 4; hh++)
                atomicMax(&ermLenc[b * 4 + hh], fenc(s[4 + hh]));
        }
    }
    // ---- Wht epilogue: bf16 transposed [bh][d][n]; block covers 128-B span ----
    #pragma unroll
    for (int rw = 0; rw < 2; rw++) {
        const int n0 = (m0 + wid * 32 + rw * 16 + quad * 4) & 2047;
        #pragma unroll
        for (int fc = 0; fc < 4; fc++) {
            int d = fc * 16 + c16;
            uint2 pk = make_uint2(
                ((uint)f32_to_bf16_rne(acc[rw][fc][0])) | (((uint)f32_to_bf16_rne(acc[rw][fc][1])) << 16),
                ((uint)f32_to_bf16_rne(acc[rw][fc][2])) | (((uint)f32_to_bf16_rne(acc[rw][fc][3])) << 16));
            *(uint2*)&Wht[((size_t)(b * 4 + nb) * 64 + d) * N_ + n0] = pk;
        }
    }
}

// ---------------------------------------------------------------------------
// Kernel 2: attention. Grid (bh=32, itile=32) so XCD = bh%8: each XCD's L2
// keeps its 4 bh-slices of Wht resident across all 32 i-blocks.
// Block = 4 waves x 16 i = 64 i. Single-buffer LDS + register prefetch.
// p_ij = max(Pi*Ej, Ri*Fj) — branchless, no transcendentals in the loop.
// ---------------------------------------------------------------------------
#define TPA 80   // pitch (ushorts) = 160 B

__global__ __launch_bounds__(256, 4) void attn_kernel(const ushort* __restrict__ Wht,
                                                      const float* __restrict__ elL,
                                                      const float* __restrict__ erL,
                                                      const uint* __restrict__ ermLenc,
                                                      const float* __restrict__ bias,
                                                      float* __restrict__ out) {
    __shared__ ushort Whs[64 * TPA];
    __shared__ float E_s[64], F_s[64];
    const int t = threadIdx.x;                 // 0..255
    const int bh = blockIdx.x, b = bh >> 2, hh = bh & 3;
    const int wid = t >> 6, lane = t & 63;
    const int c16 = lane & 15, quad = lane >> 4;
    const int ibase = blockIdx.y * 64 + wid * 16;
    const int sd = t >> 3, sch = t & 7;        // staging: row (32x2), j-eighth

    const float erm = fdec(ermLenc[bh]);
    const float e_i = elL[bh * N_ + ibase + c16];
    const float xm = e_i + erm;
    const float mI = fmaxf(xm, NEG * xm);
    const float Pi = __builtin_amdgcn_exp2f(e_i - mI);
    const float Ri = __builtin_amdgcn_exp2f(NEG * e_i - mI);

    f32x4 acc[4] = {};
    f32x4 den    = {};
    const bf16x8 ones = {0x3F80, 0x3F80, 0x3F80, 0x3F80,
                         0x3F80, 0x3F80, 0x3F80, 0x3F80};
    const ushort* WhtB = Wht + (size_t)bh * 64 * N_;
    const float* erb = erL + (size_t)bh * N_;

    // prefetch tile 0 (R3-geometry: one uint4 per thread per 32-row half)
    uint4 w0 = *(const uint4*)(WhtB + (size_t)sd * N_ + sch * 8);
    uint4 w1 = *(const uint4*)(WhtB + (size_t)(sd + 32) * N_ + sch * 8);
    float ev = (t < 64) ? erb[t] : 0.f;

    for (int jt = 0; jt < 32; jt++) {
        __syncthreads();                        // prev tile consumed
        *(uint4*)&Whs[sd * TPA + sch * 8]        = w0;
        *(uint4*)&Whs[(sd + 32) * TPA + sch * 8] = w1;
        if (t < 64) {
            E_s[t] = __builtin_amdgcn_exp2f(ev);
            F_s[t] = __builtin_amdgcn_exp2f(NEG * ev);
        }
        __syncthreads();                        // tile ready
        if (jt < 31) {                          // prefetch next tile
            const int j1 = (jt + 1) * 64;
            w0 = *(const uint4*)(WhtB + (size_t)sd * N_ + j1 + sch * 8);
            w1 = *(const uint4*)(WhtB + (size_t)(sd + 32) * N_ + j1 + sch * 8);
            if (t < 64) ev = erb[j1 + t];
        }
        #pragma unroll
        for (int ks = 0; ks < 2; ks++) {
            const int jb = ks * 32 + quad * 8;
            float4 e0 = *(const float4*)&E_s[jb];
            float4 e1 = *(const float4*)&E_s[jb + 4];
            float4 f0 = *(const float4*)&F_s[jb];
            float4 f1 = *(const float4*)&F_s[jb + 4];
            float E8[8] = {e0.x, e0.y, e0.z, e0.w, e1.x, e1.y, e1.z, e1.w};
            float F8[8] = {f0.x, f0.y, f0.z, f0.w, f1.x, f1.y, f1.z, f1.w};
            bf16x8 bfr[4];
            #pragma unroll
            for (int fd = 0; fd < 4; fd++)
                bfr[fd] = *(const bf16x8*)&Whs[(fd * 16 + c16) * TPA + jb];
            uint uu[8];
            #pragma unroll
            for (int j = 0; j < 8; j++) {
                float p = fmaxf(Pi * E8[j], Ri * F8[j]);
                uu[j] = __float_as_uint(p) + 0x8000u;
            }
            union { bf16x8 v; uint u[4]; } af;
            #pragma unroll
            for (int j = 0; j < 4; j++)
                af.u[j] = __builtin_amdgcn_perm(uu[2 * j + 1], uu[2 * j], 0x07060302u);
            #pragma unroll
            for (int fd = 0; fd < 4; fd++)
                acc[fd] = __builtin_amdgcn_mfma_f32_16x16x32_bf16(af.v, bfr[fd], acc[fd], 0, 0, 0);
            den = __builtin_amdgcn_mfma_f32_16x16x32_bf16(af.v, ones, den, 0, 0, 0);
        }
    }

    float bl[4];
    #pragma unroll
    for (int fd = 0; fd < 4; fd++) bl[fd] = bias[hh * 64 + fd * 16 + c16];
    #pragma unroll
    for (int r = 0; r < 4; r++) {
        int i = ibase + quad * 4 + r;
        float inv = 1.0f / den[r];
        float* dst = out + (size_t)(b * N_ + i) * C_ + hh * 64;
        #pragma unroll
        for (int fd = 0; fd < 4; fd++)
            dst[fd * 16 + c16] = acc[fd][r] * inv + bl[fd];
    }
}

// ---------------------------------------------------------------------------
extern "C" void kernel_launch(void* const* d_in, const int* in_sizes, int n_in,
                              void* d_out, int out_size, void* d_ws, size_t ws_size,
                              hipStream_t stream) {
    const float* h     = (const float*)d_in[0];
    const float* W     = (const float*)d_in[1];
    const float* a_src = (const float*)d_in[2];
    const float* a_dst = (const float*)d_in[3];
    const float* bias  = (const float*)d_in[4];
    float* out = (float*)d_out;

    ushort* Wt_hi = (ushort*)d_ws;                       // 256*256
    ushort* Wt_lo = Wt_hi + 256 * 256;
    ushort* Wht   = Wt_lo + 256 * 256;                   // M_*C_ bf16 [bh][d][n]
    float*  wproj = (float*)(Wht + (size_t)M_ * C_);     // 256*8
    float*  elL   = wproj + 256 * 8;
    float*  erL   = elL + 32 * N_;
    uint*   ermLe = (uint*)(erL + 32 * N_);              // 32 encoded maxima

    wprep_kernel<<<64, 256, 0, stream>>>(W, a_src, a_dst, Wt_hi, Wt_lo, wproj, ermLe);
    gemm_fused<<<dim3(256, 4), 128, 0, stream>>>(h, Wt_hi, Wt_lo, wproj, Wht, elL, erL, ermLe);
    attn_kernel<<<dim3(32, 32), 256, 0, stream>>>(Wht, elL, erL, ermLe, bias, out);
}

// Round 9
// 146.895 us; speedup vs baseline: 1.3448x; 1.0377x over previous
//
#include <hip/hip_runtime.h>
#include <math.h>

#define B_   8
#define N_   2048
#define IN_  256
#define H_   4
#define D_   64
#define C_   256            // H_*D_
#define M_   (B_*N_)        // 16384
#define NEG  0.2f
#define LOG2E 1.4426950408889634f

typedef short bf16x8 __attribute__((ext_vector_type(8)));
typedef float f32x4  __attribute__((ext_vector_type(4)));

__device__ inline ushort f32_to_bf16_rne(float x) {
    union { float f; unsigned u; } c; c.f = x;
    unsigned u = c.u + 0x7FFFu + ((c.u >> 16) & 1u);
    return (ushort)(u >> 16);
}
__device__ inline float bf16_hi_to_f32(ushort u) {
    union { unsigned u; float f; } c; c.u = ((unsigned)u) << 16;
    return c.f;
}

// ---------------------------------------------------------------------------
// Kernel 0: wprep (64 blocks).
//  - wproj[k][0..3]=LOG2E*W·a_src, [4..7]=LOG2E*W·a_dst (wave per k row)
//  - Wt_hi/Wt_lo[c][k]: split-cast transposed W
// ---------------------------------------------------------------------------
__global__ __launch_bounds__(256) void wprep_kernel(const float* __restrict__ W,
                                                    const float* __restrict__ a_src,
                                                    const float* __restrict__ a_dst,
                                                    ushort* __restrict__ Wt_hi,
                                                    ushort* __restrict__ Wt_lo,
                                                    float* __restrict__ wproj) {
    const int t = threadIdx.x, blk = blockIdx.x;
    {
        const int w = t >> 6, lane = t & 63;
        const int k = blk * 4 + w;
        float4 wv = *(const float4*)&W[k * 256 + lane * 4];
        float4 as = *(const float4*)&a_src[lane * 4];
        float4 ad = *(const float4*)&a_dst[lane * 4];
        float ss = wv.x * as.x + wv.y * as.y + wv.z * as.z + wv.w * as.w;
        float sd = wv.x * ad.x + wv.y * ad.y + wv.z * ad.z + wv.w * ad.w;
        #pragma unroll
        for (int off = 1; off < 16; off <<= 1) {
            ss += __shfl_xor(ss, off);
            sd += __shfl_xor(sd, off);
        }
        if ((lane & 15) == 0) {
            int hh = lane >> 4;
            wproj[k * 8 + hh]     = ss * LOG2E;
            wproj[k * 8 + 4 + hh] = sd * LOG2E;
        }
    }
    {
        ushort his[4], los[4];
        #pragma unroll
        for (int kk = 0; kk < 4; kk++) {
            float v = W[(blk * 4 + kk) * 256 + t];
            ushort hi = f32_to_bf16_rne(v);
            his[kk] = hi;
            los[kk] = f32_to_bf16_rne(v - bf16_hi_to_f32(hi));
        }
        *(uint2*)&Wt_hi[(size_t)t * 256 + blk * 4] =
            make_uint2(((uint)his[0]) | (((uint)his[1]) << 16), ((uint)his[2]) | (((uint)his[3]) << 16));
        *(uint2*)&Wt_lo[(size_t)t * 256 + blk * 4] =
            make_uint2(((uint)los[0]) | (((uint)los[1]) << 16), ((uint)los[2]) | (((uint)los[3]) << 16));
    }
}

// ---------------------------------------------------------------------------
// Kernel 1: cast h -> h_hi/h_lo (bf16 split) AND E/F/G score factors:
//   e = LOG2E*el, r = LOG2E*er (via h·wproj, f32 exact path)
//   E = 2^r, F = 2^(0.2r), G = 2^(-0.8e)
// Softmax scale-invariance: alpha_ij = q_ij/sum_j q_ij with
//   q_ij = max(E_j, G_i*F_j)  (exp2 distributes over lrelu's two branches)
// Block = 32 rows x 8 lanes/row (32 k each).
// ---------------------------------------------------------------------------
__global__ __launch_bounds__(256) void cast_kernel(const float* __restrict__ h,
                                                   const float* __restrict__ wproj,
                                                   ushort* __restrict__ h_hi,
                                                   ushort* __restrict__ h_lo,
                                                   float* __restrict__ E,
                                                   float* __restrict__ F,
                                                   float* __restrict__ G) {
    const int t = threadIdx.x;
    const int row_l = t >> 3, part = t & 7;
    const int m  = blockIdx.x * 32 + row_l;
    const int k0 = part * 32;
    const float* src = h + (size_t)m * 256 + k0;

    float s[8] = {};
    uint hp[16], lp[16];
    #pragma unroll
    for (int q = 0; q < 8; q++) {
        float4 hv = *(const float4*)(src + q * 4);
        float v[4] = {hv.x, hv.y, hv.z, hv.w};
        uint hu[4], lu[4];
        #pragma unroll
        for (int e = 0; e < 4; e++) {
            int kk = k0 + q * 4 + e;
            float4 w0 = *(const float4*)(wproj + kk * 8);
            float4 w1 = *(const float4*)(wproj + kk * 8 + 4);
            s[0] += v[e] * w0.x; s[1] += v[e] * w0.y;
            s[2] += v[e] * w0.z; s[3] += v[e] * w0.w;
            s[4] += v[e] * w1.x; s[5] += v[e] * w1.y;
            s[6] += v[e] * w1.z; s[7] += v[e] * w1.w;
            ushort hb = f32_to_bf16_rne(v[e]);
            float lo  = v[e] - bf16_hi_to_f32(hb);
            hu[e] = hb; lu[e] = f32_to_bf16_rne(lo);
        }
        hp[q * 2]     = hu[0] | (hu[1] << 16);
        hp[q * 2 + 1] = hu[2] | (hu[3] << 16);
        lp[q * 2]     = lu[0] | (lu[1] << 16);
        lp[q * 2 + 1] = lu[2] | (lu[3] << 16);
    }
    ushort* dh = h_hi + (size_t)m * 256 + k0;
    ushort* dl = h_lo + (size_t)m * 256 + k0;
    #pragma unroll
    for (int q = 0; q < 4; q++) {
        *(uint4*)(dh + q * 8) = make_uint4(hp[q * 4], hp[q * 4 + 1], hp[q * 4 + 2], hp[q * 4 + 3]);
        *(uint4*)(dl + q * 8) = make_uint4(lp[q * 4], lp[q * 4 + 1], lp[q * 4 + 2], lp[q * 4 + 3]);
    }
    #pragma unroll
    for (int off = 1; off < 8; off <<= 1)
        #pragma unroll
        for (int c = 0; c < 8; c++) s[c] += __shfl_xor(s[c], off);
    if (part == 0) {
        int b = m >> 11, n = m & 2047;
        #pragma unroll
        for (int hh = 0; hh < 4; hh++) {
            int idx = (b * 4 + hh) * N_ + n;
            float e = s[hh], r = s[4 + hh];
            E[idx] = __builtin_amdgcn_exp2f(r);
            F[idx] = __builtin_amdgcn_exp2f(NEG * r);
            G[idx] = __builtin_amdgcn_exp2f(-0.8f * e);
        }
    }
}

// ---------------------------------------------------------------------------
// Kernel 2: bf16 split MFMA GEMM, BARRIER-FREE K-loop.
// Grid (128, 4) = 512 blocks x 256 thr (4 waves). Block: 128 m x 64 c (1 head).
// B (64 c x 256 k, hi+lo) staged in LDS ONCE; A-frags streamed from global
// (bf16, pre-split by cast) with 1-slice register prefetch. No __syncthreads
// in the K-loop -> waves fully decoupled. 3 MFMAs/frag ~ f32 accuracy.
// Epilogue transposes through LDS so Wht stores are 256-B contiguous rows.
// ---------------------------------------------------------------------------
#define BP 264   // B LDS pitch (ushorts): uniform bank spread for b128 frags
#define EP 136   // epilogue LDS pitch (ushorts) for 128-n rows

__global__ __launch_bounds__(256, 2) void gemm_bf16(const ushort* __restrict__ h_hi,
                                                    const ushort* __restrict__ h_lo,
                                                    const ushort* __restrict__ Wt_hi,
                                                    const ushort* __restrict__ Wt_lo,
                                                    ushort* __restrict__ Wht) {
    __shared__ ushort Bs_h[64 * BP], Bs_l[64 * BP];

    const int t = threadIdx.x;                 // 0..255
    const int m0 = blockIdx.x * 128;
    const int nb = blockIdx.y;                 // head (c-tile 64 == head)
    const int b  = m0 >> 11;
    const int wid = t >> 6, lane = t & 63;
    const int c16 = lane & 15, quad = lane >> 4;

    // ---- stage B once: thread = (c = t>>2, k-quarter = t&3), 128 B each ----
    {
        const int c = t >> 2, kq = t & 3;
        const ushort* sh = Wt_hi + (size_t)(nb * 64 + c) * 256 + kq * 64;
        const ushort* sl = Wt_lo + (size_t)(nb * 64 + c) * 256 + kq * 64;
        ushort* dh = &Bs_h[c * BP + kq * 64];
        ushort* dl = &Bs_l[c * BP + kq * 64];
        #pragma unroll
        for (int q = 0; q < 8; q++) {
            *(uint4*)(dh + q * 8) = *(const uint4*)(sh + q * 8);
            *(uint4*)(dl + q * 8) = *(const uint4*)(sl + q * 8);
        }
    }

    const int row0 = m0 + wid * 32 + c16;      // rw=0 row; rw=1 is +16
    const ushort* ah0 = h_hi + (size_t)row0 * 256 + quad * 8;
    const ushort* al0 = h_lo + (size_t)row0 * 256 + quad * 8;
    const ushort* ah1 = ah0 + 16 * 256;
    const ushort* al1 = al0 + 16 * 256;

    // prefetch A slice 0
    bf16x8 pa_h[2], pa_l[2];
    pa_h[0] = *(const bf16x8*)ah0;  pa_l[0] = *(const bf16x8*)al0;
    pa_h[1] = *(const bf16x8*)ah1;  pa_l[1] = *(const bf16x8*)al1;

    __syncthreads();                            // B staged (only barrier pre-epilogue)

    f32x4 acc[2][4] = {};
    for (int k0 = 0; k0 < 256; k0 += 32) {
        bf16x8 a_h0 = pa_h[0], a_l0 = pa_l[0];
        bf16x8 a_h1 = pa_h[1], a_l1 = pa_l[1];
        if (k0 < 224) {                         // prefetch next slice
            pa_h[0] = *(const bf16x8*)(ah0 + k0 + 32);
            pa_l[0] = *(const bf16x8*)(al0 + k0 + 32);
            pa_h[1] = *(const bf16x8*)(ah1 + k0 + 32);
            pa_l[1] = *(const bf16x8*)(al1 + k0 + 32);
        }
        #pragma unroll
        for (int fc = 0; fc < 4; fc++) {
            bf16x8 bhf = *(const bf16x8*)&Bs_h[(fc * 16 + c16) * BP + k0 + quad * 8];
            bf16x8 blf = *(const bf16x8*)&Bs_l[(fc * 16 + c16) * BP + k0 + quad * 8];
            acc[0][fc] = __builtin_amdgcn_mfma_f32_16x16x32_bf16(a_h0, bhf, acc[0][fc], 0, 0, 0);
            acc[0][fc] = __builtin_amdgcn_mfma_f32_16x16x32_bf16(a_l0, bhf, acc[0][fc], 0, 0, 0);
            acc[0][fc] = __builtin_amdgcn_mfma_f32_16x16x32_bf16(a_h0, blf, acc[0][fc], 0, 0, 0);
            acc[1][fc] = __builtin_amdgcn_mfma_f32_16x16x32_bf16(a_h1, bhf, acc[1][fc], 0, 0, 0);
            acc[1][fc] = __builtin_amdgcn_mfma_f32_16x16x32_bf16(a_l1, bhf, acc[1][fc], 0, 0, 0);
            acc[1][fc] = __builtin_amdgcn_mfma_f32_16x16x32_bf16(a_h1, blf, acc[1][fc], 0, 0, 0);
        }
    }

    // ---- epilogue: transpose via LDS (reuse Bs_h), 256-B contiguous stores --
    __syncthreads();                            // everyone done with Bs
    ushort* Es = Bs_h;                          // [64 d][EP] layout
    #pragma unroll
    for (int rw = 0; rw < 2; rw++) {
        const int nloc = wid * 32 + rw * 16 + quad * 4;
        #pragma unroll
        for (int fc = 0; fc < 4; fc++) {
            const int d = fc * 16 + c16;
            uint2 pk = make_uint2(
                ((uint)f32_to_bf16_rne(acc[rw][fc][0])) | (((uint)f32_to_bf16_rne(acc[rw][fc][1])) << 16),
                ((uint)f32_to_bf16_rne(acc[rw][fc][2])) | (((uint)f32_to_bf16_rne(acc[rw][fc][3])) << 16));
            *(uint2*)&Es[d * EP + nloc] = pk;
        }
    }
    __syncthreads();
    {
        const int d = t >> 2, ch = t & 3;       // 64 d-rows x 4 chunks of 32 n
        ushort* dst = Wht + ((size_t)(b * 4 + nb) * 64 + d) * N_ + (m0 & 2047) + ch * 32;
        const ushort* srcl = &Es[d * EP + ch * 32];
        #pragma unroll
        for (int q = 0; q < 4; q++)
            *(uint4*)(dst + q * 8) = *(const uint4*)(srcl + q * 8);
    }
}

// ---------------------------------------------------------------------------
// Kernel 3: attention, normalization-free: q = max(Ej, Gi*Fj) (1 mul + 1 max),
// den via ones-MFMA, Pi cancels in acc/den. Grid (bh=32, itile=32), 256 thr
// (4 waves x 16 i). Double-buffered LDS: ONE barrier per j-tile.
// ---------------------------------------------------------------------------
#define TPA 80   // pitch (ushorts) = 160 B (measured conflict-free)

__global__ __launch_bounds__(256, 4) void attn_kernel(const ushort* __restrict__ Wht,
                                                      const float* __restrict__ E,
                                                      const float* __restrict__ F,
                                                      const float* __restrict__ G,
                                                      const float* __restrict__ bias,
                                                      float* __restrict__ out) {
    __shared__ ushort Whs[2][64 * TPA];
    __shared__ float E_s[2][64], F_s[2][64];
    const int t = threadIdx.x;                 // 0..255
    const int bh = blockIdx.x, b = bh >> 2, hh = bh & 3;
    const int wid = t >> 6, lane = t & 63;
    const int c16 = lane & 15, quad = lane >> 4;
    const int ibase = blockIdx.y * 64 + wid * 16;
    const int sd = t >> 3, sch = t & 7;        // staging: d-row (32x2), j-eighth

    const float Gi = G[bh * N_ + ibase + c16];

    f32x4 acc[4] = {};
    f32x4 den    = {};
    const bf16x8 ones = {0x3F80, 0x3F80, 0x3F80, 0x3F80,
                         0x3F80, 0x3F80, 0x3F80, 0x3F80};
    const ushort* WhtB = Wht + (size_t)bh * 64 * N_;
    const float* Eb = E + (size_t)bh * N_;
    const float* Fb = F + (size_t)bh * N_;

    // prefetch tile 0
    uint4 w0 = *(const uint4*)(WhtB + (size_t)sd * N_ + sch * 8);
    uint4 w1 = *(const uint4*)(WhtB + (size_t)(sd + 32) * N_ + sch * 8);
    float ev_e = 0.f, ev_f = 0.f;
    if (t < 64) { ev_e = Eb[t]; ev_f = Fb[t]; }

    for (int jt = 0; jt < 32; jt++) {
        const int buf = jt & 1;
        *(uint4*)&Whs[buf][sd * TPA + sch * 8]        = w0;
        *(uint4*)&Whs[buf][(sd + 32) * TPA + sch * 8] = w1;
        if (t < 64) { E_s[buf][t] = ev_e; F_s[buf][t] = ev_f; }
        if (jt < 31) {                          // prefetch next tile
            const int j1 = (jt + 1) * 64;
            w0 = *(const uint4*)(WhtB + (size_t)sd * N_ + j1 + sch * 8);
            w1 = *(const uint4*)(WhtB + (size_t)(sd + 32) * N_ + j1 + sch * 8);
            if (t < 64) { ev_e = Eb[j1 + t]; ev_f = Fb[j1 + t]; }
        }
        __syncthreads();                        // tile[buf] ready
        #pragma unroll
        for (int ks = 0; ks < 2; ks++) {
            const int jb = ks * 32 + quad * 8;
            float4 e0 = *(const float4*)&E_s[buf][jb];
            float4 e1 = *(const float4*)&E_s[buf][jb + 4];
            float4 f0 = *(const float4*)&F_s[buf][jb];
            float4 f1 = *(const float4*)&F_s[buf][jb + 4];
            float E8[8] = {e0.x, e0.y, e0.z, e0.w, e1.x, e1.y, e1.z, e1.w};
            float F8[8] = {f0.x, f0.y, f0.z, f0.w, f1.x, f1.y, f1.z, f1.w};
            bf16x8 bfr[4];
            #pragma unroll
            for (int fd = 0; fd < 4; fd++)
                bfr[fd] = *(const bf16x8*)&Whs[buf][(fd * 16 + c16) * TPA + jb];
            uint uu[8];
            #pragma unroll
            for (int j = 0; j < 8; j++) {
                float q = fmaxf(E8[j], Gi * F8[j]);
                uu[j] = __float_as_uint(q) + 0x8000u;
            }
            union { bf16x8 v; uint u[4]; } af;
            #pragma unroll
            for (int j = 0; j < 4; j++)
                af.u[j] = __builtin_amdgcn_perm(uu[2 * j + 1], uu[2 * j], 0x07060302u);
            #pragma unroll
            for (int fd = 0; fd < 4; fd++)
                acc[fd] = __builtin_amdgcn_mfma_f32_16x16x32_bf16(af.v, bfr[fd], acc[fd], 0, 0, 0);
            den = __builtin_amdgcn_mfma_f32_16x16x32_bf16(af.v, ones, den, 0, 0, 0);
        }
    }

    float bl[4];
    #pragma unroll
    for (int fd = 0; fd < 4; fd++) bl[fd] = bias[hh * 64 + fd * 16 + c16];
    #pragma unroll
    for (int r = 0; r < 4; r++) {
        int i = ibase + quad * 4 + r;
        float inv = 1.0f / den[r];
        float* dst = out + (size_t)(b * N_ + i) * C_ + hh * 64;
        #pragma unroll
        for (int fd = 0; fd < 4; fd++)
            dst[fd * 16 + c16] = acc[fd][r] * inv + bl[fd];
    }
}

// ---------------------------------------------------------------------------
extern "C" void kernel_launch(void* const* d_in, const int* in_sizes, int n_in,
                              void* d_out, int out_size, void* d_ws, size_t ws_size,
                              hipStream_t stream) {
    const float* h     = (const float*)d_in[0];
    const float* W     = (const float*)d_in[1];
    const float* a_src = (const float*)d_in[2];
    const float* a_dst = (const float*)d_in[3];
    const float* bias  = (const float*)d_in[4];
    float* out = (float*)d_out;

    ushort* h_hi  = (ushort*)d_ws;                       // M_*IN_ bf16 (8 MB)
    ushort* h_lo  = h_hi + (size_t)M_ * IN_;             // 8 MB
    ushort* Wt_hi = h_lo + (size_t)M_ * IN_;             // 128 KB [c][k]
    ushort* Wt_lo = Wt_hi + 256 * 256;                   // 128 KB
    ushort* Wht   = Wt_lo + 256 * 256;                   // M_*C_ bf16 (8 MB) [bh][d][n]
    float*  wproj = (float*)(Wht + (size_t)M_ * C_);     // 256*8
    float*  E     = wproj + 256 * 8;                     // 32*2048
    float*  F     = E + 32 * N_;                         // 32*2048
    float*  G     = F + 32 * N_;                         // 32*2048

    wprep_kernel<<<64, 256, 0, stream>>>(W, a_src, a_dst, Wt_hi, Wt_lo, wproj);
    cast_kernel<<<M_ / 32, 256, 0, stream>>>(h, wproj, h_hi, h_lo, E, F, G);
    gemm_bf16<<<dim3(M_ / 128, 4), 256, 0, stream>>>(h_hi, h_lo, Wt_hi, Wt_lo, Wht);
    attn_kernel<<<dim3(32, 32), 256, 0, stream>>>(Wht, E, F, G, bias, out);
}

// Round 10
// 122.822 us; speedup vs baseline: 1.6084x; 1.1960x over previous
//
#include <hip/hip_runtime.h>
#include <math.h>

#define B_   8
#define N_   2048
#define IN_  256
#define H_   4
#define D_   64
#define C_   256            // H_*D_
#define M_   (B_*N_)        // 16384
#define NEG  0.2f
#define LOG2E 1.4426950408889634f

typedef short bf16x8 __attribute__((ext_vector_type(8)));
typedef float f32x4  __attribute__((ext_vector_type(4)));

__device__ inline ushort f32_to_bf16_rne(float x) {
    union { float f; unsigned u; } c; c.f = x;
    unsigned u = c.u + 0x7FFFu + ((c.u >> 16) & 1u);
    return (ushort)(u >> 16);
}
__device__ inline float bf16_hi_to_f32(ushort u) {
    union { unsigned u; float f; } c; c.u = ((unsigned)u) << 16;
    return c.f;
}
// split 8 f32 -> hi/lo bf16x8 (in-register cast; no h_hi/h_lo round-trip)
__device__ inline void split8(const float v[8], bf16x8* hi, bf16x8* lo) {
    union { bf16x8 v; ushort u[8]; } H, L;
    #pragma unroll
    for (int j = 0; j < 8; j++) {
        ushort hb = f32_to_bf16_rne(v[j]);
        H.u[j] = hb;
        L.u[j] = f32_to_bf16_rne(v[j] - bf16_hi_to_f32(hb));
    }
    *hi = H.v; *lo = L.v;
}

// ---------------------------------------------------------------------------
// Kernel 0: wprep (64 blocks): Wt_hi/Wt_lo[c][k] = split-cast transposed W.
// ---------------------------------------------------------------------------
__global__ __launch_bounds__(256) void wprep_kernel(const float* __restrict__ W,
                                                    ushort* __restrict__ Wt_hi,
                                                    ushort* __restrict__ Wt_lo) {
    const int t = threadIdx.x, blk = blockIdx.x;
    ushort his[4], los[4];
    #pragma unroll
    for (int kk = 0; kk < 4; kk++) {
        float v = W[(blk * 4 + kk) * 256 + t];
        ushort hi = f32_to_bf16_rne(v);
        his[kk] = hi;
        los[kk] = f32_to_bf16_rne(v - bf16_hi_to_f32(hi));
    }
    *(uint2*)&Wt_hi[(size_t)t * 256 + blk * 4] =
        make_uint2(((uint)his[0]) | (((uint)his[1]) << 16), ((uint)his[2]) | (((uint)his[3]) << 16));
    *(uint2*)&Wt_lo[(size_t)t * 256 + blk * 4] =
        make_uint2(((uint)los[0]) | (((uint)los[1]) << 16), ((uint)los[2]) | (((uint)los[3]) << 16));
}

// ---------------------------------------------------------------------------
// Kernel 1: fused GEMM (barrier-free K-loop) + in-register cast + scores.
// Grid (128, 4) = 512 blocks x 256 thr. Block: 128 m x 64 c (1 head).
// A: f32 h from global, split hi/lo in-register, 1-slice prefetch.
// B: LDS staged once. 3 MFMAs/frag ~ f32 accuracy. No barrier in K-loop.
// Epilogue: (a) scores from acc (el=Wh·a_src exact-f32) -> E=2^r, F=2^(.2r),
// G=2^(-.8e); (b) Wht bf16 transpose via LDS, 256-B contiguous stores.
// ---------------------------------------------------------------------------
#define BP 264   // B LDS pitch (ushorts)
#define EP 136   // epilogue LDS pitch (ushorts)

__global__ __launch_bounds__(256, 2) void gemm_fused(const float* __restrict__ h,
                                                     const ushort* __restrict__ Wt_hi,
                                                     const ushort* __restrict__ Wt_lo,
                                                     const float* __restrict__ a_src,
                                                     const float* __restrict__ a_dst,
                                                     ushort* __restrict__ Wht,
                                                     float* __restrict__ Ee,
                                                     float* __restrict__ Ff,
                                                     float* __restrict__ Gg) {
    __shared__ ushort Bs_h[64 * BP], Bs_l[64 * BP];

    const int t = threadIdx.x;
    const int m0 = blockIdx.x * 128;
    const int nb = blockIdx.y;                 // head
    const int b  = m0 >> 11;
    const int wid = t >> 6, lane = t & 63;
    const int c16 = lane & 15, quad = lane >> 4;

    // ---- stage B once: thread = (c = t>>2, k-quarter = t&3) ----
    {
        const int c = t >> 2, kq = t & 3;
        const ushort* sh = Wt_hi + (size_t)(nb * 64 + c) * 256 + kq * 64;
        const ushort* sl = Wt_lo + (size_t)(nb * 64 + c) * 256 + kq * 64;
        ushort* dh = &Bs_h[c * BP + kq * 64];
        ushort* dl = &Bs_l[c * BP + kq * 64];
        #pragma unroll
        for (int q = 0; q < 8; q++) {
            *(uint4*)(dh + q * 8) = *(const uint4*)(sh + q * 8);
            *(uint4*)(dl + q * 8) = *(const uint4*)(sl + q * 8);
        }
    }

    const int row0 = m0 + wid * 32 + c16;      // rw=0; rw=1 is +16
    const float* hp0 = h + (size_t)row0 * 256 + quad * 8;
    const float* hp1 = hp0 + 16 * 256;

    // prefetch A slice 0 (f32)
    float4 p0a = *(const float4*)hp0, p0b = *(const float4*)(hp0 + 4);
    float4 p1a = *(const float4*)hp1, p1b = *(const float4*)(hp1 + 4);

    __syncthreads();                            // B staged

    f32x4 acc[2][4] = {};
    for (int k0 = 0; k0 < 256; k0 += 32) {
        float v0[8] = {p0a.x, p0a.y, p0a.z, p0a.w, p0b.x, p0b.y, p0b.z, p0b.w};
        float v1[8] = {p1a.x, p1a.y, p1a.z, p1a.w, p1b.x, p1b.y, p1b.z, p1b.w};
        if (k0 < 224) {                         // prefetch next slice
            p0a = *(const float4*)(hp0 + k0 + 32); p0b = *(const float4*)(hp0 + k0 + 36);
            p1a = *(const float4*)(hp1 + k0 + 32); p1b = *(const float4*)(hp1 + k0 + 36);
        }
        bf16x8 ah0, al0, ah1, al1;
        split8(v0, &ah0, &al0);
        split8(v1, &ah1, &al1);
        #pragma unroll
        for (int fc = 0; fc < 4; fc++) {
            bf16x8 bhf = *(const bf16x8*)&Bs_h[(fc * 16 + c16) * BP + k0 + quad * 8];
            bf16x8 blf = *(const bf16x8*)&Bs_l[(fc * 16 + c16) * BP + k0 + quad * 8];
            acc[0][fc] = __builtin_amdgcn_mfma_f32_16x16x32_bf16(ah0, bhf, acc[0][fc], 0, 0, 0);
            acc[0][fc] = __builtin_amdgcn_mfma_f32_16x16x32_bf16(al0, bhf, acc[0][fc], 0, 0, 0);
            acc[0][fc] = __builtin_amdgcn_mfma_f32_16x16x32_bf16(ah0, blf, acc[0][fc], 0, 0, 0);
            acc[1][fc] = __builtin_amdgcn_mfma_f32_16x16x32_bf16(ah1, bhf, acc[1][fc], 0, 0, 0);
            acc[1][fc] = __builtin_amdgcn_mfma_f32_16x16x32_bf16(al1, bhf, acc[1][fc], 0, 0, 0);
            acc[1][fc] = __builtin_amdgcn_mfma_f32_16x16x32_bf16(ah1, blf, acc[1][fc], 0, 0, 0);
        }
    }

    // ---- scores epilogue: el/er from acc (exact f32), butterfly over c16 ----
    {
        float avs[4], avd[4];
        #pragma unroll
        for (int fc = 0; fc < 4; fc++) {
            avs[fc] = a_src[nb * 64 + fc * 16 + c16];
            avd[fc] = a_dst[nb * 64 + fc * 16 + c16];
        }
        float ds[2][4] = {}, dd[2][4] = {};
        #pragma unroll
        for (int rw = 0; rw < 2; rw++)
            #pragma unroll
            for (int r = 0; r < 4; r++)
                #pragma unroll
                for (int fc = 0; fc < 4; fc++) {
                    ds[rw][r] += acc[rw][fc][r] * avs[fc];
                    dd[rw][r] += acc[rw][fc][r] * avd[fc];
                }
        #pragma unroll
        for (int off = 1; off < 16; off <<= 1)
            #pragma unroll
            for (int rw = 0; rw < 2; rw++)
                #pragma unroll
                for (int r = 0; r < 4; r++) {
                    ds[rw][r] += __shfl_xor(ds[rw][r], off);
                    dd[rw][r] += __shfl_xor(dd[rw][r], off);
                }
        if (c16 == 0) {
            #pragma unroll
            for (int rw = 0; rw < 2; rw++)
                #pragma unroll
                for (int r = 0; r < 4; r++) {
                    int m = m0 + wid * 32 + rw * 16 + quad * 4 + r;
                    int idx = (b * 4 + nb) * N_ + (m & 2047);
                    float ee = ds[rw][r] * LOG2E;   // el (log2-domain)
                    float rr = dd[rw][r] * LOG2E;   // er (log2-domain)
                    Ee[idx] = __builtin_amdgcn_exp2f(rr);
                    Ff[idx] = __builtin_amdgcn_exp2f(NEG * rr);
                    Gg[idx] = __builtin_amdgcn_exp2f(-0.8f * ee);
                }
        }
    }

    // ---- Wht epilogue: transpose via LDS (reuse Bs_h), 256-B stores ----
    __syncthreads();
    ushort* Es = Bs_h;
    #pragma unroll
    for (int rw = 0; rw < 2; rw++) {
        const int nloc = wid * 32 + rw * 16 + quad * 4;
        #pragma unroll
        for (int fc = 0; fc < 4; fc++) {
            const int d = fc * 16 + c16;
            uint2 pk = make_uint2(
                ((uint)f32_to_bf16_rne(acc[rw][fc][0])) | (((uint)f32_to_bf16_rne(acc[rw][fc][1])) << 16),
                ((uint)f32_to_bf16_rne(acc[rw][fc][2])) | (((uint)f32_to_bf16_rne(acc[rw][fc][3])) << 16));
            *(uint2*)&Es[d * EP + nloc] = pk;
        }
    }
    __syncthreads();
    {
        const int d = t >> 2, ch = t & 3;
        ushort* dst = Wht + ((size_t)(b * 4 + nb) * 64 + d) * N_ + (m0 & 2047) + ch * 32;
        const ushort* srcl = &Es[d * EP + ch * 32];
        #pragma unroll
        for (int q = 0; q < 4; q++)
            *(uint4*)(dst + q * 8) = *(const uint4*)(srcl + q * 8);
    }
}

// ---------------------------------------------------------------------------
// Kernel 2: attention. q_ij = max(E_j, G_i*F_j) (normalization-free; per-i
// scale cancels in acc/den). Grid (bh=32, itile=16): XCD = bh%8 L2 locality.
// Block = 256 thr, 4 waves x 32 i (g=2) = 128 i: B-frag LDS reads amortized
// over 2x MFMA vs R9. Double-buffered LDS, one barrier per j-tile.
// ---------------------------------------------------------------------------
#define TPA 80   // pitch (ushorts) = 160 B (measured conflict-free)

__global__ __launch_bounds__(256, 2) void attn_kernel(const ushort* __restrict__ Wht,
                                                      const float* __restrict__ Ee,
                                                      const float* __restrict__ Ff,
                                                      const float* __restrict__ Gg,
                                                      const float* __restrict__ bias,
                                                      float* __restrict__ out) {
    __shared__ ushort Whs[2][64 * TPA];
    __shared__ float E_s[2][64], F_s[2][64];
    const int t = threadIdx.x;
    const int bh = blockIdx.x, b = bh >> 2, hh = bh & 3;
    const int wid = t >> 6, lane = t & 63;
    const int c16 = lane & 15, quad = lane >> 4;
    const int ibase = blockIdx.y * 128 + wid * 32;
    const int sd = t >> 3, sch = t & 7;        // staging: d-row (32x2), j-eighth

    float Gi[2];
    #pragma unroll
    for (int g = 0; g < 2; g++) Gi[g] = Gg[bh * N_ + ibase + g * 16 + c16];

    f32x4 acc[2][4] = {};
    f32x4 den[2] = {};
    const bf16x8 ones = {0x3F80, 0x3F80, 0x3F80, 0x3F80,
                         0x3F80, 0x3F80, 0x3F80, 0x3F80};
    const ushort* WhtB = Wht + (size_t)bh * 64 * N_;
    const float* Eb = Ee + (size_t)bh * N_;
    const float* Fb = Ff + (size_t)bh * N_;

    // prefetch tile 0
    uint4 w0 = *(const uint4*)(WhtB + (size_t)sd * N_ + sch * 8);
    uint4 w1 = *(const uint4*)(WhtB + (size_t)(sd + 32) * N_ + sch * 8);
    float ev_e = 0.f, ev_f = 0.f;
    if (t < 64) { ev_e = Eb[t]; ev_f = Fb[t]; }

    for (int jt = 0; jt < 32; jt++) {
        const int buf = jt & 1;
        *(uint4*)&Whs[buf][sd * TPA + sch * 8]        = w0;
        *(uint4*)&Whs[buf][(sd + 32) * TPA + sch * 8] = w1;
        if (t < 64) { E_s[buf][t] = ev_e; F_s[buf][t] = ev_f; }
        if (jt < 31) {                          // prefetch next tile
            const int j1 = (jt + 1) * 64;
            w0 = *(const uint4*)(WhtB + (size_t)sd * N_ + j1 + sch * 8);
            w1 = *(const uint4*)(WhtB + (size_t)(sd + 32) * N_ + j1 + sch * 8);
            if (t < 64) { ev_e = Eb[j1 + t]; ev_f = Fb[j1 + t]; }
        }
        __syncthreads();                        // tile[buf] ready
        #pragma unroll
        for (int ks = 0; ks < 2; ks++) {
            const int jb = ks * 32 + quad * 8;
            float4 e0 = *(const float4*)&E_s[buf][jb];
            float4 e1 = *(const float4*)&E_s[buf][jb + 4];
            float4 f0 = *(const float4*)&F_s[buf][jb];
            float4 f1 = *(const float4*)&F_s[buf][jb + 4];
            float E8[8] = {e0.x, e0.y, e0.z, e0.w, e1.x, e1.y, e1.z, e1.w};
            float F8[8] = {f0.x, f0.y, f0.z, f0.w, f1.x, f1.y, f1.z, f1.w};
            bf16x8 bfr[4];
            #pragma unroll
            for (int fd = 0; fd < 4; fd++)
                bfr[fd] = *(const bf16x8*)&Whs[buf][(fd * 16 + c16) * TPA + jb];
            #pragma unroll
            for (int g = 0; g < 2; g++) {
                const float gi = Gi[g];
                uint uu[8];
                #pragma unroll
                for (int j = 0; j < 8; j++) {
                    float q = fmaxf(E8[j], gi * F8[j]);
                    uu[j] = __float_as_uint(q) + 0x8000u;
                }
                union { bf16x8 v; uint u[4]; } af;
                #pragma unroll
                for (int j = 0; j < 4; j++)
                    af.u[j] = __builtin_amdgcn_perm(uu[2 * j + 1], uu[2 * j], 0x07060302u);
                #pragma unroll
                for (int fd = 0; fd < 4; fd++)
                    acc[g][fd] = __builtin_amdgcn_mfma_f32_16x16x32_bf16(af.v, bfr[fd], acc[g][fd], 0, 0, 0);
                den[g] = __builtin_amdgcn_mfma_f32_16x16x32_bf16(af.v, ones, den[g], 0, 0, 0);
            }
        }
    }

    float bl[4];
    #pragma unroll
    for (int fd = 0; fd < 4; fd++) bl[fd] = bias[hh * 64 + fd * 16 + c16];
    #pragma unroll
    for (int g = 0; g < 2; g++)
        #pragma unroll
        for (int r = 0; r < 4; r++) {
            int i = ibase + g * 16 + quad * 4 + r;
            float inv = 1.0f / den[g][r];
            float* dst = out + (size_t)(b * N_ + i) * C_ + hh * 64;
            #pragma unroll
            for (int fd = 0; fd < 4; fd++)
                dst[fd * 16 + c16] = acc[g][fd][r] * inv + bl[fd];
        }
}

// ---------------------------------------------------------------------------
extern "C" void kernel_launch(void* const* d_in, const int* in_sizes, int n_in,
                              void* d_out, int out_size, void* d_ws, size_t ws_size,
                              hipStream_t stream) {
    const float* h     = (const float*)d_in[0];
    const float* W     = (const float*)d_in[1];
    const float* a_src = (const float*)d_in[2];
    const float* a_dst = (const float*)d_in[3];
    const float* bias  = (const float*)d_in[4];
    float* out = (float*)d_out;

    ushort* Wt_hi = (ushort*)d_ws;                       // 256*256
    ushort* Wt_lo = Wt_hi + 256 * 256;
    ushort* Wht   = Wt_lo + 256 * 256;                   // M_*C_ bf16 [bh][d][n]
    float*  Ee    = (float*)(Wht + (size_t)M_ * C_);     // 32*2048
    float*  Ff    = Ee + 32 * N_;
    float*  Gg    = Ff + 32 * N_;

    wprep_kernel<<<64, 256, 0, stream>>>(W, Wt_hi, Wt_lo);
    gemm_fused<<<dim3(M_ / 128, 4), 256, 0, stream>>>(h, Wt_hi, Wt_lo, a_src, a_dst,
                                                      Wht, Ee, Ff, Gg);
    attn_kernel<<<dim3(32, 16), 256, 0, stream>>>(Wht, Ee, Ff, Gg, bias, out);
}